// Round 1
// baseline (687.424 us; speedup 1.0000x reference)
//
#include <hip/hip_runtime.h>
#include <cstdint>
#include <cstddef>

typedef float f4 __attribute__((ext_vector_type(4)));
typedef float f2 __attribute__((ext_vector_type(2)));
typedef short short8 __attribute__((ext_vector_type(8)));

#define NB 128
#define NH 512
#define NS 400
#define NV 50000

__device__ __forceinline__ unsigned short f2bf(float f) {
  unsigned u = __float_as_uint(f);
  u = u + 0x7fffu + ((u >> 16) & 1u);   // RTNE
  return (unsigned short)(u >> 16);
}

// ---------------- K1: gi/gh GEMMs ----------------
// C[128][3072]: cols 0..1535 = emb@Wih^T, cols 1536..3071 = hid@Whh^T
// BM=64, BN=32, BK=32, 256 thr, thread tile 4x2. grid (96, 2).
__global__ __launch_bounds__(256) void k1_gigh(
    const float* __restrict__ emb, const float* __restrict__ hid,
    const float* __restrict__ Wih, const float* __restrict__ Whh,
    float* __restrict__ C)
{
  __shared__ float As[32 * 68];   // [k][m], padded
  __shared__ float Bs[32 * 36];   // [k][n], padded
  const int tid = threadIdx.x;
  const int n0g = blockIdx.x * 32;
  const int m0  = blockIdx.y * 64;
  const float* A; const float* Bm; int n0;
  if (n0g < 1536) { A = emb; Bm = Wih; n0 = n0g; }
  else            { A = hid; Bm = Whh; n0 = n0g - 1536; }
  const int mt = tid & 15, nt = tid >> 4;
  const int arow = tid >> 2, ac = tid & 3;
  const int brow = tid >> 3, bc = tid & 7;
  float acc[4][2] = {};
  for (int k0 = 0; k0 < 512; k0 += 32) {
    f4 x0 = *(const f4*)(A + (m0 + arow) * 512 + k0 + ac * 8);
    f4 x1 = *(const f4*)(A + (m0 + arow) * 512 + k0 + ac * 8 + 4);
    f4 y  = *(const f4*)(Bm + (n0 + brow) * 512 + k0 + bc * 4);
    __syncthreads();
#pragma unroll
    for (int kk = 0; kk < 4; kk++) {
      As[(ac * 8 + kk) * 68 + arow]     = x0[kk];
      As[(ac * 8 + 4 + kk) * 68 + arow] = x1[kk];
      Bs[(bc * 4 + kk) * 36 + brow]     = y[kk];
    }
    __syncthreads();
#pragma unroll
    for (int kk = 0; kk < 32; kk++) {
      f4 a = *(const f4*)(As + kk * 68 + mt * 4);
      f2 b = *(const f2*)(Bs + kk * 36 + nt * 2);
#pragma unroll
      for (int i = 0; i < 4; i++) {
        acc[i][0] += a[i] * b[0];
        acc[i][1] += a[i] * b[1];
      }
    }
  }
#pragma unroll
  for (int i = 0; i < 4; i++) {
    f2 o; o[0] = acc[i][0]; o[1] = acc[i][1];
    *(f2*)(C + (size_t)(m0 + mt * 4 + i) * 3072 + n0g + nt * 2) = o;
  }
}

// ---------------- K2: GRU gates -> h_new ----------------
__global__ __launch_bounds__(256) void k2_gates(
    const float* __restrict__ gigh, const float* __restrict__ hid,
    const float* __restrict__ bih, const float* __restrict__ bhh,
    float* __restrict__ out_h, float* __restrict__ comb,
    unsigned short* __restrict__ cbf)
{
  int i = blockIdx.x * 256 + threadIdx.x;   // 65536
  int b = i >> 9, j = i & 511;
  const float* gg = gigh + b * 3072;
  float ir  = gg[j]        + bih[j];
  float iz  = gg[j + 512]  + bih[j + 512];
  float in_ = gg[j + 1024] + bih[j + 1024];
  float hr  = gg[j + 1536] + bhh[j];
  float hz  = gg[j + 2048] + bhh[j + 512];
  float hn  = gg[j + 2560] + bhh[j + 1024];
  float r = 1.f / (1.f + expf(-(ir + hr)));
  float z = 1.f / (1.f + expf(-(iz + hz)));
  float n = tanhf(in_ + r * hn);
  float hnew = (1.f - z) * n + z * hid[i];
  out_h[i] = hnew;
  comb[b * 1024 + j] = hnew;
  cbf[b * 1024 + j] = f2bf(hnew);
}

// ---------------- K3: v = h_new @ W_bil (NN, coalesced j) ----------------
__global__ __launch_bounds__(256) void k3_v(
    const float* __restrict__ comb, const float* __restrict__ Wbil,
    float* __restrict__ v)
{
  int i = blockIdx.x * 256 + threadIdx.x;   // 65536
  int b = i >> 9, j = i & 511;
  const float* x = comb + b * 1024;         // h_new part
  float acc = 0.f;
#pragma unroll 8
  for (int h = 0; h < 512; h++) acc += x[h] * Wbil[h * 512 + j];
  v[i] = acc;
}

// ---------------- K4a: energy[s,b] = v[b].enc[s,b] (one wave per (s,b)) ----
__global__ __launch_bounds__(256) void k4_energy(
    const float* __restrict__ enc, const float* __restrict__ v,
    const float* __restrict__ bbil, float* __restrict__ energy)  // [b][400]
{
  int tid = threadIdx.x;
  int gw = blockIdx.x * 4 + (tid >> 6);   // 0..51199
  int lane = tid & 63;
  int s = gw >> 7, b = gw & 127;
  const float* er = enc + ((size_t)(s * 128 + b)) * 512 + lane * 8;
  const float* vr = v + b * 512 + lane * 8;
  f4 e0 = *(const f4*)er, e1 = *(const f4*)(er + 4);
  f4 v0 = *(const f4*)vr, v1 = *(const f4*)(vr + 4);
  float d = e0[0]*v0[0] + e0[1]*v0[1] + e0[2]*v0[2] + e0[3]*v0[3]
          + e1[0]*v1[0] + e1[1]*v1[1] + e1[2]*v1[2] + e1[3]*v1[3];
#pragma unroll
  for (int o = 32; o; o >>= 1) d += __shfl_xor(d, o);
  if (lane == 0) energy[b * 400 + s] = d + bbil[0];
}

// ---------------- K4b: softmax over s (in-place), also writes enc_attn ----
__global__ __launch_bounds__(256) void k4_softmax(
    float* __restrict__ energy, float* __restrict__ out_attn)
{
  __shared__ float sm[4];
  int b = blockIdx.x, tid = threadIdx.x;
  float* e = energy + b * 400;
  float e0 = (tid < 400)       ? e[tid]       : -3.4e38f;
  float e1 = (tid + 256 < 400) ? e[tid + 256] : -3.4e38f;
  float m = fmaxf(e0, e1);
#pragma unroll
  for (int o = 32; o; o >>= 1) m = fmaxf(m, __shfl_xor(m, o));
  if ((tid & 63) == 0) sm[tid >> 6] = m;
  __syncthreads();
  m = fmaxf(fmaxf(sm[0], sm[1]), fmaxf(sm[2], sm[3]));
  __syncthreads();
  float x0 = (tid < 400)       ? expf(e0 - m) : 0.f;
  float x1 = (tid + 256 < 400) ? expf(e1 - m) : 0.f;
  float s = x0 + x1;
#pragma unroll
  for (int o = 32; o; o >>= 1) s += __shfl_xor(s, o);
  if ((tid & 63) == 0) sm[tid >> 6] = s;
  __syncthreads();
  s = sm[0] + sm[1] + sm[2] + sm[3];
  float inv = 1.f / s;
  if (tid < 400)       { float a = x0 * inv; e[tid] = a;       out_attn[b * 400 + tid] = a; }
  if (tid + 256 < 400) { float a = x1 * inv; e[tid + 256] = a; out_attn[b * 400 + tid + 256] = a; }
}

// ---------------- K4c: context[b,h] = sum_s attn[b,s]*enc[s,b,h] ----------
__global__ __launch_bounds__(256) void k4_context(
    const float* __restrict__ enc, const float* __restrict__ attn,
    float* __restrict__ comb, unsigned short* __restrict__ cbf)
{
  __shared__ float at[400];
  int b = blockIdx.y, ht = blockIdx.x, tid = threadIdx.x;
  for (int i = tid; i < 400; i += 256) at[i] = attn[b * 400 + i];
  __syncthreads();
  int h = ht * 256 + tid;
  const float* ep = enc + (size_t)b * 512 + h;
  float acc = 0.f;
#pragma unroll 4
  for (int s = 0; s < 400; s++) acc += at[s] * ep[(size_t)s * 65536];
  comb[b * 1024 + 512 + h] = acc;
  cbf[b * 1024 + 512 + h] = f2bf(acc);
}

// ---------------- K_p: prob_ptr ----------------
__global__ __launch_bounds__(64) void k_pptr(
    const float* __restrict__ comb, const float* __restrict__ Wptr,
    const float* __restrict__ bptr, float* __restrict__ out_p,
    float* __restrict__ p)
{
  int b = blockIdx.x, lane = threadIdx.x;
  const float* x = comb + b * 1024;
  float d = 0.f;
#pragma unroll
  for (int i = 0; i < 16; i++) d += x[i * 64 + lane] * Wptr[i * 64 + lane];
#pragma unroll
  for (int o = 32; o; o >>= 1) d += __shfl_xor(d, o);
  if (lane == 0) {
    float pv = 1.f / (1.f + expf(-(d + bptr[0])));
    out_p[b] = pv;
    p[b] = pv;
  }
}

// ---------------- K5a: logits = combined(bf16) @ W_out^T + b_out ----------
// grid 782 blocks x 256 thr (4 waves). Wave covers 16 v; block BN=64; M=128.
// No LDS: W streamed from HBM (f32 -> bf16 in regs), A from L1/L2.
__global__ __launch_bounds__(256) void k5_logits(
    const unsigned short* __restrict__ Abf, const float* __restrict__ W,
    const float* __restrict__ bout, float* __restrict__ out)
{
  int tid = threadIdx.x;
  int wave = tid >> 6, lane = tid & 63;
  int quad = lane >> 4, l16 = lane & 15;
  int v = blockIdx.x * 64 + wave * 16 + l16;
  int vc = v < NV ? v : NV - 1;
  const float* wrow = W + (size_t)vc * 1024 + quad * 8;
  const unsigned short* arow = Abf + l16 * 1024 + quad * 8;
  f4 acc[8] = {};
#pragma unroll 2
  for (int k = 0; k < 1024; k += 32) {
    f4 w0 = *(const f4*)(wrow + k);
    f4 w1 = *(const f4*)(wrow + k + 4);
    short8 bfrag;
    bfrag[0] = (short)f2bf(w0[0]); bfrag[1] = (short)f2bf(w0[1]);
    bfrag[2] = (short)f2bf(w0[2]); bfrag[3] = (short)f2bf(w0[3]);
    bfrag[4] = (short)f2bf(w1[0]); bfrag[5] = (short)f2bf(w1[1]);
    bfrag[6] = (short)f2bf(w1[2]); bfrag[7] = (short)f2bf(w1[3]);
#pragma unroll
    for (int mt = 0; mt < 8; mt++) {
      short8 afrag = *(const short8*)(arow + mt * 16 * 1024 + k);
      acc[mt] = __builtin_amdgcn_mfma_f32_16x16x32_bf16(afrag, bfrag, acc[mt], 0, 0, 0);
    }
  }
  if (v < NV) {
    float bias = bout[v];
#pragma unroll
    for (int mt = 0; mt < 8; mt++) {
#pragma unroll
      for (int r = 0; r < 4; r++) {
        int bb = mt * 16 + quad * 4 + r;   // C/D: col=lane&15, row=quad*4+reg
        out[(size_t)bb * NV + v] = acc[mt][r] + bias;
      }
    }
  }
}

// ---------------- K5b: per-row max & sumexp -> t[b] ----------------
__global__ __launch_bounds__(256) void k5_stats(
    const float* __restrict__ out, const float* __restrict__ p,
    float* __restrict__ t)
{
  __shared__ float sm[4];
  int b = blockIdx.x, tid = threadIdx.x;
  const float* L = out + (size_t)b * NV;
  float m = -3.4e38f;
  for (int vv = tid; vv < NV; vv += 256) m = fmaxf(m, L[vv]);
#pragma unroll
  for (int o = 32; o; o >>= 1) m = fmaxf(m, __shfl_xor(m, o));
  if ((tid & 63) == 0) sm[tid >> 6] = m;
  __syncthreads();
  float M = fmaxf(fmaxf(sm[0], sm[1]), fmaxf(sm[2], sm[3]));
  __syncthreads();
  float s = 0.f;
  for (int vv = tid; vv < NV; vv += 256) s += expf(L[vv] - M);
#pragma unroll
  for (int o = 32; o; o >>= 1) s += __shfl_xor(s, o);
  if ((tid & 63) == 0) sm[tid >> 6] = s;
  __syncthreads();
  if (tid == 0) {
    float S = sm[0] + sm[1] + sm[2] + sm[3];
    t[b] = -M - logf(S) + logf(1.f - p[b]);
  }
}

// ---------------- K5d: out = logit + t[b]  (== log((1-p)*gen)) ------------
__global__ __launch_bounds__(256) void k5_shift(
    float* __restrict__ out, const float* __restrict__ t)
{
  int vv = blockIdx.x * 256 + threadIdx.x;
  int b = blockIdx.y;
  if (vv < NV) out[(size_t)b * NV + vv] += t[b];
}

// ---------------- K5e: sparse pointer mix via CAS: log(exp(x)+p*attn) -----
__global__ __launch_bounds__(256) void k5_scatter(
    const int* __restrict__ idx, const float* __restrict__ p,
    const float* __restrict__ attn, float* __restrict__ out)
{
  int i = blockIdx.x * 256 + threadIdx.x;
  if (i >= NS * NB) return;
  int s = i >> 7, b = i & 127;            // idx layout (S,B)
  float add = p[b] * attn[b * 400 + s];
  int* ai = (int*)(out + (size_t)b * NV + idx[i]);
  int cur = *ai;
  while (true) {
    float oldf = __int_as_float(cur);
    float nv = logf(expf(oldf) + add);
    int got = atomicCAS(ai, cur, __float_as_int(nv));
    if (got == cur) break;
    cur = got;
  }
}

extern "C" void kernel_launch(void* const* d_in, const int* in_sizes, int n_in,
                              void* d_out, int out_size, void* d_ws, size_t ws_size,
                              hipStream_t stream) {
  (void)in_sizes; (void)n_in; (void)out_size; (void)ws_size;
  const float* emb  = (const float*)d_in[0];
  const float* hid  = (const float*)d_in[1];
  const float* enc  = (const float*)d_in[2];
  const int*   widx = (const int*)d_in[3];
  const float* Wih  = (const float*)d_in[5];
  const float* Whh  = (const float*)d_in[6];
  const float* bih  = (const float*)d_in[7];
  const float* bhh  = (const float*)d_in[8];
  const float* Wbil = (const float*)d_in[9];
  const float* bbil = (const float*)d_in[10];
  const float* Wout = (const float*)d_in[11];
  const float* bout = (const float*)d_in[12];
  const float* Wptr = (const float*)d_in[13];
  const float* bptr = (const float*)d_in[14];

  float* out      = (float*)d_out;
  float* out_logp = out;                 // 128*50000
  float* out_h    = out + 6400000;       // 128*512
  float* out_attn = out + 6465536;       // 128*400
  float* out_p    = out + 6516736;       // 128

  float* ws   = (float*)d_ws;
  float* gigh = ws;                      // 393216
  float* comb = ws + 393216;             // 131072 (f32 combined [b][1024])
  float* vws  = ws + 524288;             // 65536
  float* attn = ws + 589824;             // 51200 (energy -> attn in place)
  float* pws  = ws + 641024;             // 128
  float* tws  = ws + 641152;             // 128
  unsigned short* cbf = (unsigned short*)(ws + 641280);  // 131072 ushorts

  k1_gigh   <<<dim3(96, 2),   256, 0, stream>>>(emb, hid, Wih, Whh, gigh);
  k2_gates  <<<256,           256, 0, stream>>>(gigh, hid, bih, bhh, out_h, comb, cbf);
  k3_v      <<<256,           256, 0, stream>>>(comb, Wbil, vws);
  k4_energy <<<12800,         256, 0, stream>>>(enc, vws, bbil, attn);
  k4_softmax<<<128,           256, 0, stream>>>(attn, out_attn);
  k4_context<<<dim3(2, 128),  256, 0, stream>>>(enc, attn, comb, cbf);
  k_pptr    <<<128,            64, 0, stream>>>(comb, Wptr, bptr, out_p, pws);
  k5_logits <<<782,           256, 0, stream>>>(cbf, Wout, bout, out_logp);
  k5_stats  <<<128,           256, 0, stream>>>(out_logp, pws, tws);
  k5_shift  <<<dim3(196, 128),256, 0, stream>>>(out_logp, tws);
  k5_scatter<<<200,           256, 0, stream>>>(widx, pws, attn, out_logp);
}

// Round 2
// 554.150 us; speedup vs baseline: 1.2405x; 1.2405x over previous
//
#include <hip/hip_runtime.h>
#include <cstdint>
#include <cstddef>

typedef float f4 __attribute__((ext_vector_type(4)));
typedef float f2 __attribute__((ext_vector_type(2)));
typedef short short8 __attribute__((ext_vector_type(8)));

#define NB 128
#define NH 512
#define NS 400
#define NV 50000

__device__ __forceinline__ unsigned short f2bf(float f) {
  unsigned u = __float_as_uint(f);
  u = u + 0x7fffu + ((u >> 16) & 1u);   // RTNE
  return (unsigned short)(u >> 16);
}

// bf16 A staged in MFMA-fragment order so k5 can ds_read_b128 contiguously.
// chunk c = k>>7 (BK=128), step t = (k>>5)&3, quad q = (k>>3)&3, o = k&7,
// mt = m>>4, l16 = m&15. Flat (halves):
// c*16384 + t*4096 + mt*512 + (q*16+l16)*8 + o
__device__ __forceinline__ int fragidx(int m, int k) {
  int c = k >> 7;
  int t = (k >> 5) & 3;
  int q = (k >> 3) & 3;
  int o = k & 7;
  return ((((c * 4 + t) * 8 + (m >> 4)) * 64) + q * 16 + (m & 15)) * 8 + o;
}

// ---------------- K1: gi/gh GEMMs ----------------
__global__ __launch_bounds__(256) void k1_gigh(
    const float* __restrict__ emb, const float* __restrict__ hid,
    const float* __restrict__ Wih, const float* __restrict__ Whh,
    float* __restrict__ C)
{
  __shared__ float As[32 * 68];   // [k][m], padded
  __shared__ float Bs[32 * 36];   // [k][n], padded
  const int tid = threadIdx.x;
  const int n0g = blockIdx.x * 32;
  const int m0  = blockIdx.y * 64;
  const float* A; const float* Bm; int n0;
  if (n0g < 1536) { A = emb; Bm = Wih; n0 = n0g; }
  else            { A = hid; Bm = Whh; n0 = n0g - 1536; }
  const int mt = tid & 15, nt = tid >> 4;
  const int arow = tid >> 2, ac = tid & 3;
  const int brow = tid >> 3, bc = tid & 7;
  float acc[4][2] = {};
  for (int k0 = 0; k0 < 512; k0 += 32) {
    f4 x0 = *(const f4*)(A + (m0 + arow) * 512 + k0 + ac * 8);
    f4 x1 = *(const f4*)(A + (m0 + arow) * 512 + k0 + ac * 8 + 4);
    f4 y  = *(const f4*)(Bm + (n0 + brow) * 512 + k0 + bc * 4);
    __syncthreads();
#pragma unroll
    for (int kk = 0; kk < 4; kk++) {
      As[(ac * 8 + kk) * 68 + arow]     = x0[kk];
      As[(ac * 8 + 4 + kk) * 68 + arow] = x1[kk];
      Bs[(bc * 4 + kk) * 36 + brow]     = y[kk];
    }
    __syncthreads();
#pragma unroll
    for (int kk = 0; kk < 32; kk++) {
      f4 a = *(const f4*)(As + kk * 68 + mt * 4);
      f2 b = *(const f2*)(Bs + kk * 36 + nt * 2);
#pragma unroll
      for (int i = 0; i < 4; i++) {
        acc[i][0] += a[i] * b[0];
        acc[i][1] += a[i] * b[1];
      }
    }
  }
#pragma unroll
  for (int i = 0; i < 4; i++) {
    f2 o; o[0] = acc[i][0]; o[1] = acc[i][1];
    *(f2*)(C + (size_t)(m0 + mt * 4 + i) * 3072 + n0g + nt * 2) = o;
  }
}

// ---------------- K2: GRU gates -> h_new ----------------
__global__ __launch_bounds__(256) void k2_gates(
    const float* __restrict__ gigh, const float* __restrict__ hid,
    const float* __restrict__ bih, const float* __restrict__ bhh,
    float* __restrict__ out_h, float* __restrict__ comb,
    unsigned short* __restrict__ cbf)
{
  int i = blockIdx.x * 256 + threadIdx.x;   // 65536
  int b = i >> 9, j = i & 511;
  const float* gg = gigh + b * 3072;
  float ir  = gg[j]        + bih[j];
  float iz  = gg[j + 512]  + bih[j + 512];
  float in_ = gg[j + 1024] + bih[j + 1024];
  float hr  = gg[j + 1536] + bhh[j];
  float hz  = gg[j + 2048] + bhh[j + 512];
  float hn  = gg[j + 2560] + bhh[j + 1024];
  float r = 1.f / (1.f + expf(-(ir + hr)));
  float z = 1.f / (1.f + expf(-(iz + hz)));
  float n = tanhf(in_ + r * hn);
  float hnew = (1.f - z) * n + z * hid[i];
  out_h[i] = hnew;
  comb[b * 1024 + j] = hnew;
  cbf[fragidx(b, j)] = f2bf(hnew);
}

// ---------------- K3: v = h_new @ W_bil (NN, coalesced j) ----------------
__global__ __launch_bounds__(256) void k3_v(
    const float* __restrict__ comb, const float* __restrict__ Wbil,
    float* __restrict__ v)
{
  int i = blockIdx.x * 256 + threadIdx.x;   // 65536
  int b = i >> 9, j = i & 511;
  const float* x = comb + b * 1024;         // h_new part
  float acc = 0.f;
#pragma unroll 8
  for (int h = 0; h < 512; h++) acc += x[h] * Wbil[h * 512 + j];
  v[i] = acc;
}

// ---------------- K4a: energy[s,b] = v[b].enc[s,b] (one wave per (s,b)) ----
__global__ __launch_bounds__(256) void k4_energy(
    const float* __restrict__ enc, const float* __restrict__ v,
    const float* __restrict__ bbil, float* __restrict__ energy)  // [b][400]
{
  int tid = threadIdx.x;
  int gw = blockIdx.x * 4 + (tid >> 6);   // 0..51199
  int lane = tid & 63;
  int s = gw >> 7, b = gw & 127;
  const float* er = enc + ((size_t)(s * 128 + b)) * 512 + lane * 8;
  const float* vr = v + b * 512 + lane * 8;
  f4 e0 = *(const f4*)er, e1 = *(const f4*)(er + 4);
  f4 v0 = *(const f4*)vr, v1 = *(const f4*)(vr + 4);
  float d = e0[0]*v0[0] + e0[1]*v0[1] + e0[2]*v0[2] + e0[3]*v0[3]
          + e1[0]*v1[0] + e1[1]*v1[1] + e1[2]*v1[2] + e1[3]*v1[3];
#pragma unroll
  for (int o = 32; o; o >>= 1) d += __shfl_xor(d, o);
  if (lane == 0) energy[b * 400 + s] = d + bbil[0];
}

// ---------------- K4b: softmax over s (in-place), also writes enc_attn ----
__global__ __launch_bounds__(256) void k4_softmax(
    float* __restrict__ energy, float* __restrict__ out_attn)
{
  __shared__ float sm[4];
  int b = blockIdx.x, tid = threadIdx.x;
  float* e = energy + b * 400;
  float e0 = (tid < 400)       ? e[tid]       : -3.4e38f;
  float e1 = (tid + 256 < 400) ? e[tid + 256] : -3.4e38f;
  float m = fmaxf(e0, e1);
#pragma unroll
  for (int o = 32; o; o >>= 1) m = fmaxf(m, __shfl_xor(m, o));
  if ((tid & 63) == 0) sm[tid >> 6] = m;
  __syncthreads();
  m = fmaxf(fmaxf(sm[0], sm[1]), fmaxf(sm[2], sm[3]));
  __syncthreads();
  float x0 = (tid < 400)       ? expf(e0 - m) : 0.f;
  float x1 = (tid + 256 < 400) ? expf(e1 - m) : 0.f;
  float s = x0 + x1;
#pragma unroll
  for (int o = 32; o; o >>= 1) s += __shfl_xor(s, o);
  if ((tid & 63) == 0) sm[tid >> 6] = s;
  __syncthreads();
  s = sm[0] + sm[1] + sm[2] + sm[3];
  float inv = 1.f / s;
  if (tid < 400)       { float a = x0 * inv; e[tid] = a;       out_attn[b * 400 + tid] = a; }
  if (tid + 256 < 400) { float a = x1 * inv; e[tid + 256] = a; out_attn[b * 400 + tid + 256] = a; }
}

// ---------------- K4c: context[b,h] = sum_s attn[b,s]*enc[s,b,h] ----------
__global__ __launch_bounds__(256) void k4_context(
    const float* __restrict__ enc, const float* __restrict__ attn,
    float* __restrict__ comb, unsigned short* __restrict__ cbf)
{
  __shared__ float at[400];
  int b = blockIdx.y, ht = blockIdx.x, tid = threadIdx.x;
  for (int i = tid; i < 400; i += 256) at[i] = attn[b * 400 + i];
  __syncthreads();
  int h = ht * 256 + tid;
  const float* ep = enc + (size_t)b * 512 + h;
  float acc = 0.f;
#pragma unroll 4
  for (int s = 0; s < 400; s++) acc += at[s] * ep[(size_t)s * 65536];
  comb[b * 1024 + 512 + h] = acc;
  cbf[fragidx(b, 512 + h)] = f2bf(acc);
}

// ---------------- K_p: prob_ptr ----------------
__global__ __launch_bounds__(64) void k_pptr(
    const float* __restrict__ comb, const float* __restrict__ Wptr,
    const float* __restrict__ bptr, float* __restrict__ out_p,
    float* __restrict__ p)
{
  int b = blockIdx.x, lane = threadIdx.x;
  const float* x = comb + b * 1024;
  float d = 0.f;
#pragma unroll
  for (int i = 0; i < 16; i++) d += x[i * 64 + lane] * Wptr[i * 64 + lane];
#pragma unroll
  for (int o = 32; o; o >>= 1) d += __shfl_xor(d, o);
  if (lane == 0) {
    float pv = 1.f / (1.f + expf(-(d + bptr[0])));
    out_p[b] = pv;
    p[b] = pv;
  }
}

// ---------------- K5a: logits = combined(bf16) @ W_out^T + b_out ----------
// m97-style: A (fragment-order bf16) staged in LDS per BK=128 chunk (32 KB);
// each wave computes 32 v (2 B-frags), block = 2 waves = 64 v, grid 782.
// W f32 streamed from HBM with one-step register prefetch, cvt to bf16 in
// VALU. ds_reads conflict-free (lanes contiguous 16B).
__global__ __launch_bounds__(128) void k5_logits(
    const unsigned short* __restrict__ Abf, const float* __restrict__ W,
    const float* __restrict__ bout, float* __restrict__ out)
{
  __shared__ __align__(16) unsigned short As[16384];  // 32 KB, one BK=128 chunk
  const int tid = threadIdx.x;
  const int wid = tid >> 6, lane = tid & 63;
  const int quad = lane >> 4, l16 = lane & 15;
  const int vb = blockIdx.x * 64 + wid * 32;
  const int v0 = vb + l16;
  const int v1 = vb + 16 + l16;
  const size_t r0 = (size_t)(v0 < NV ? v0 : NV - 1) * 1024 + quad * 8;
  const size_t r1 = (size_t)(v1 < NV ? v1 : NV - 1) * 1024 + quad * 8;
  f4 acc0[8] = {}, acc1[8] = {};
  // prefetch W for step 0
  f4 wa0 = *(const f4*)(W + r0);
  f4 wa1 = *(const f4*)(W + r0 + 4);
  f4 wb0 = *(const f4*)(W + r1);
  f4 wb1 = *(const f4*)(W + r1 + 4);
  for (int c = 0; c < 8; c++) {
    const f4* src = (const f4*)(Abf + c * 16384);
    f4* dst = (f4*)As;
    __syncthreads();
#pragma unroll 4
    for (int j = 0; j < 16; j++) dst[j * 128 + tid] = src[j * 128 + tid];
    __syncthreads();
#pragma unroll
    for (int t = 0; t < 4; t++) {
      // convert current W regs to bf16 B-fragments
      short8 b0, b1;
      b0[0] = (short)f2bf(wa0[0]); b0[1] = (short)f2bf(wa0[1]);
      b0[2] = (short)f2bf(wa0[2]); b0[3] = (short)f2bf(wa0[3]);
      b0[4] = (short)f2bf(wa1[0]); b0[5] = (short)f2bf(wa1[1]);
      b0[6] = (short)f2bf(wa1[2]); b0[7] = (short)f2bf(wa1[3]);
      b1[0] = (short)f2bf(wb0[0]); b1[1] = (short)f2bf(wb0[1]);
      b1[2] = (short)f2bf(wb0[2]); b1[3] = (short)f2bf(wb0[3]);
      b1[4] = (short)f2bf(wb1[0]); b1[5] = (short)f2bf(wb1[1]);
      b1[6] = (short)f2bf(wb1[2]); b1[7] = (short)f2bf(wb1[3]);
      // prefetch next step's W (stays on vmcnt, overlaps MFMA below)
      int kn = c * 128 + (t + 1) * 32;
      if (kn < 1024) {
        wa0 = *(const f4*)(W + r0 + kn); wa1 = *(const f4*)(W + r0 + kn + 4);
        wb0 = *(const f4*)(W + r1 + kn); wb1 = *(const f4*)(W + r1 + kn + 4);
      }
      const short8* afp = (const short8*)(As + t * 4096);
#pragma unroll
      for (int mt = 0; mt < 8; mt++) {
        short8 af = afp[mt * 64 + lane];
        acc0[mt] = __builtin_amdgcn_mfma_f32_16x16x32_bf16(af, b0, acc0[mt], 0, 0, 0);
        acc1[mt] = __builtin_amdgcn_mfma_f32_16x16x32_bf16(af, b1, acc1[mt], 0, 0, 0);
      }
    }
  }
  if (v0 < NV) {
    float bias = bout[v0];
#pragma unroll
    for (int mt = 0; mt < 8; mt++)
#pragma unroll
      for (int r = 0; r < 4; r++)
        out[(size_t)(mt * 16 + quad * 4 + r) * NV + v0] = acc0[mt][r] + bias;
  }
  if (v1 < NV) {
    float bias = bout[v1];
#pragma unroll
    for (int mt = 0; mt < 8; mt++)
#pragma unroll
      for (int r = 0; r < 4; r++)
        out[(size_t)(mt * 16 + quad * 4 + r) * NV + v1] = acc1[mt][r] + bias;
  }
}

// ---------------- K5b: per-row max & sumexp -> t[b] ----------------
__global__ __launch_bounds__(1024) void k5_stats(
    const float* __restrict__ out, const float* __restrict__ p,
    float* __restrict__ t)
{
  __shared__ float sm[16];
  int b = blockIdx.x, tid = threadIdx.x;
  const float* L = out + (size_t)b * NV;
  float m = -3.4e38f;
  for (int vv = tid; vv < NV; vv += 1024) m = fmaxf(m, L[vv]);
#pragma unroll
  for (int o = 32; o; o >>= 1) m = fmaxf(m, __shfl_xor(m, o));
  if ((tid & 63) == 0) sm[tid >> 6] = m;
  __syncthreads();
  float M = sm[0];
#pragma unroll
  for (int i = 1; i < 16; i++) M = fmaxf(M, sm[i]);
  __syncthreads();
  float s = 0.f;
  for (int vv = tid; vv < NV; vv += 1024) s += expf(L[vv] - M);
#pragma unroll
  for (int o = 32; o; o >>= 1) s += __shfl_xor(s, o);
  if ((tid & 63) == 0) sm[tid >> 6] = s;
  __syncthreads();
  if (tid == 0) {
    float S = 0.f;
#pragma unroll
    for (int i = 0; i < 16; i++) S += sm[i];
    t[b] = -M - logf(S) + logf(1.f - p[b]);
  }
}

// ---------------- K5d: out = logit + t[b]  (== log((1-p)*gen)) ------------
__global__ __launch_bounds__(256) void k5_shift(
    float* __restrict__ out, const float* __restrict__ t)
{
  int vv = blockIdx.x * 256 + threadIdx.x;
  int b = blockIdx.y;
  if (vv < NV) out[(size_t)b * NV + vv] += t[b];
}

// ---------------- K5e: sparse pointer mix via CAS: log(exp(x)+p*attn) -----
__global__ __launch_bounds__(256) void k5_scatter(
    const int* __restrict__ idx, const float* __restrict__ p,
    const float* __restrict__ attn, float* __restrict__ out)
{
  int i = blockIdx.x * 256 + threadIdx.x;
  if (i >= NS * NB) return;
  int s = i >> 7, b = i & 127;            // idx layout (S,B)
  float add = p[b] * attn[b * 400 + s];
  int* ai = (int*)(out + (size_t)b * NV + idx[i]);
  int cur = *ai;
  while (true) {
    float oldf = __int_as_float(cur);
    float nv = logf(expf(oldf) + add);
    int got = atomicCAS(ai, cur, __float_as_int(nv));
    if (got == cur) break;
    cur = got;
  }
}

extern "C" void kernel_launch(void* const* d_in, const int* in_sizes, int n_in,
                              void* d_out, int out_size, void* d_ws, size_t ws_size,
                              hipStream_t stream) {
  (void)in_sizes; (void)n_in; (void)out_size; (void)ws_size;
  const float* emb  = (const float*)d_in[0];
  const float* hid  = (const float*)d_in[1];
  const float* enc  = (const float*)d_in[2];
  const int*   widx = (const int*)d_in[3];
  const float* Wih  = (const float*)d_in[5];
  const float* Whh  = (const float*)d_in[6];
  const float* bih  = (const float*)d_in[7];
  const float* bhh  = (const float*)d_in[8];
  const float* Wbil = (const float*)d_in[9];
  const float* bbil = (const float*)d_in[10];
  const float* Wout = (const float*)d_in[11];
  const float* bout = (const float*)d_in[12];
  const float* Wptr = (const float*)d_in[13];
  const float* bptr = (const float*)d_in[14];

  float* out      = (float*)d_out;
  float* out_logp = out;                 // 128*50000
  float* out_h    = out + 6400000;       // 128*512
  float* out_attn = out + 6465536;       // 128*400
  float* out_p    = out + 6516736;       // 128

  float* ws   = (float*)d_ws;
  float* gigh = ws;                      // 393216
  float* comb = ws + 393216;             // 131072 (f32 combined [b][1024])
  float* vws  = ws + 524288;             // 65536
  float* attn = ws + 589824;             // 51200 (energy -> attn in place)
  float* pws  = ws + 641024;             // 128
  float* tws  = ws + 641152;             // 128
  unsigned short* cbf = (unsigned short*)(ws + 641280);  // 131072 ushorts, frag order

  k1_gigh   <<<dim3(96, 2),   256, 0, stream>>>(emb, hid, Wih, Whh, gigh);
  k2_gates  <<<256,           256, 0, stream>>>(gigh, hid, bih, bhh, out_h, comb, cbf);
  k3_v      <<<256,           256, 0, stream>>>(comb, Wbil, vws);
  k4_energy <<<12800,         256, 0, stream>>>(enc, vws, bbil, attn);
  k4_softmax<<<128,           256, 0, stream>>>(attn, out_attn);
  k4_context<<<dim3(2, 128),  256, 0, stream>>>(enc, attn, comb, cbf);
  k_pptr    <<<128,            64, 0, stream>>>(comb, Wptr, bptr, out_p, pws);
  k5_logits <<<782,           128, 0, stream>>>(cbf, Wout, bout, out_logp);
  k5_stats  <<<128,          1024, 0, stream>>>(out_logp, pws, tws);
  k5_shift  <<<dim3(196, 128),256, 0, stream>>>(out_logp, tws);
  k5_scatter<<<200,           256, 0, stream>>>(widx, pws, attn, out_logp);
}

// Round 3
// 508.518 us; speedup vs baseline: 1.3518x; 1.0897x over previous
//
#include <hip/hip_runtime.h>
#include <cstdint>
#include <cstddef>

typedef float f4 __attribute__((ext_vector_type(4)));
typedef float f2 __attribute__((ext_vector_type(2)));
typedef short short8 __attribute__((ext_vector_type(8)));

#define NB 128
#define NH 512
#define NS 400
#define NV 50000
#define NEGBIG (-3.402823466e38f)

__device__ __forceinline__ unsigned short f2bf(float f) {
  unsigned u = __float_as_uint(f);
  u = u + 0x7fffu + ((u >> 16) & 1u);   // RTNE
  return (unsigned short)(u >> 16);
}

// bf16 A staged in MFMA-fragment order so k5 can ds_read_b128 contiguously.
// chunk c = k>>7 (BK=128), step t = (k>>5)&3, quad q = (k>>3)&3, o = k&7,
// mt = m>>4, l16 = m&15. Flat (halves):
// c*16384 + t*4096 + mt*512 + (q*16+l16)*8 + o
__device__ __forceinline__ int fragidx(int m, int k) {
  int c = k >> 7;
  int t = (k >> 5) & 3;
  int q = (k >> 3) & 3;
  int o = k & 7;
  return ((((c * 4 + t) * 8 + (m >> 4)) * 64) + q * 16 + (m & 15)) * 8 + o;
}

// ---------------- K1: gi/gh GEMMs ----------------
__global__ __launch_bounds__(256) void k1_gigh(
    const float* __restrict__ emb, const float* __restrict__ hid,
    const float* __restrict__ Wih, const float* __restrict__ Whh,
    float* __restrict__ C)
{
  __shared__ float As[32 * 68];   // [k][m], padded
  __shared__ float Bs[32 * 36];   // [k][n], padded
  const int tid = threadIdx.x;
  const int n0g = blockIdx.x * 32;
  const int m0  = blockIdx.y * 64;
  const float* A; const float* Bm; int n0;
  if (n0g < 1536) { A = emb; Bm = Wih; n0 = n0g; }
  else            { A = hid; Bm = Whh; n0 = n0g - 1536; }
  const int mt = tid & 15, nt = tid >> 4;
  const int arow = tid >> 2, ac = tid & 3;
  const int brow = tid >> 3, bc = tid & 7;
  float acc[4][2] = {};
  for (int k0 = 0; k0 < 512; k0 += 32) {
    f4 x0 = *(const f4*)(A + (m0 + arow) * 512 + k0 + ac * 8);
    f4 x1 = *(const f4*)(A + (m0 + arow) * 512 + k0 + ac * 8 + 4);
    f4 y  = *(const f4*)(Bm + (n0 + brow) * 512 + k0 + bc * 4);
    __syncthreads();
#pragma unroll
    for (int kk = 0; kk < 4; kk++) {
      As[(ac * 8 + kk) * 68 + arow]     = x0[kk];
      As[(ac * 8 + 4 + kk) * 68 + arow] = x1[kk];
      Bs[(bc * 4 + kk) * 36 + brow]     = y[kk];
    }
    __syncthreads();
#pragma unroll
    for (int kk = 0; kk < 32; kk++) {
      f4 a = *(const f4*)(As + kk * 68 + mt * 4);
      f2 b = *(const f2*)(Bs + kk * 36 + nt * 2);
#pragma unroll
      for (int i = 0; i < 4; i++) {
        acc[i][0] += a[i] * b[0];
        acc[i][1] += a[i] * b[1];
      }
    }
  }
#pragma unroll
  for (int i = 0; i < 4; i++) {
    f2 o; o[0] = acc[i][0]; o[1] = acc[i][1];
    *(f2*)(C + (size_t)(m0 + mt * 4 + i) * 3072 + n0g + nt * 2) = o;
  }
}

// ---------------- K2: GRU gates -> h_new ----------------
__global__ __launch_bounds__(256) void k2_gates(
    const float* __restrict__ gigh, const float* __restrict__ hid,
    const float* __restrict__ bih, const float* __restrict__ bhh,
    float* __restrict__ out_h, float* __restrict__ comb,
    unsigned short* __restrict__ cbf)
{
  int i = blockIdx.x * 256 + threadIdx.x;   // 65536
  int b = i >> 9, j = i & 511;
  const float* gg = gigh + b * 3072;
  float ir  = gg[j]        + bih[j];
  float iz  = gg[j + 512]  + bih[j + 512];
  float in_ = gg[j + 1024] + bih[j + 1024];
  float hr  = gg[j + 1536] + bhh[j];
  float hz  = gg[j + 2048] + bhh[j + 512];
  float hn  = gg[j + 2560] + bhh[j + 1024];
  float r = 1.f / (1.f + expf(-(ir + hr)));
  float z = 1.f / (1.f + expf(-(iz + hz)));
  float n = tanhf(in_ + r * hn);
  float hnew = (1.f - z) * n + z * hid[i];
  out_h[i] = hnew;
  comb[b * 1024 + j] = hnew;
  cbf[fragidx(b, j)] = f2bf(hnew);
}

// ---------------- K3: v = h_new @ W_bil (NN, coalesced j) ----------------
__global__ __launch_bounds__(256) void k3_v(
    const float* __restrict__ comb, const float* __restrict__ Wbil,
    float* __restrict__ v)
{
  int i = blockIdx.x * 256 + threadIdx.x;   // 65536
  int b = i >> 9, j = i & 511;
  const float* x = comb + b * 1024;         // h_new part
  float acc = 0.f;
#pragma unroll 16
  for (int h = 0; h < 512; h++) acc += x[h] * Wbil[h * 512 + j];
  v[i] = acc;
}

// ---------------- K4a: energy[s,b] — one wave per (b, 8 s-values) ---------
__global__ __launch_bounds__(128) void k4_energy(
    const float* __restrict__ enc, const float* __restrict__ v,
    const float* __restrict__ bbil, float* __restrict__ energy)  // [b][400]
{
  int tid = threadIdx.x;
  int wid = tid >> 6, lane = tid & 63;
  int b = blockIdx.y;
  int sc = blockIdx.x * 2 + wid;            // 0..49
  const float* vr = v + b * 512 + lane * 8;
  f4 v0 = *(const f4*)vr, v1 = *(const f4*)(vr + 4);
  float e[8];
#pragma unroll
  for (int i = 0; i < 8; i++) {
    int s = sc * 8 + i;
    const float* er = enc + ((size_t)(s * 128 + b)) * 512 + lane * 8;
    f4 e0 = *(const f4*)er, e1 = *(const f4*)(er + 4);
    e[i] = e0[0]*v0[0] + e0[1]*v0[1] + e0[2]*v0[2] + e0[3]*v0[3]
         + e1[0]*v1[0] + e1[1]*v1[1] + e1[2]*v1[2] + e1[3]*v1[3];
  }
#pragma unroll
  for (int i = 0; i < 8; i++)
#pragma unroll
    for (int o = 32; o; o >>= 1) e[i] += __shfl_xor(e[i], o);
  if (lane == 0) {
    float bb = bbil[0];
    f4 o0, o1;
    o0[0] = e[0] + bb; o0[1] = e[1] + bb; o0[2] = e[2] + bb; o0[3] = e[3] + bb;
    o1[0] = e[4] + bb; o1[1] = e[5] + bb; o1[2] = e[6] + bb; o1[3] = e[7] + bb;
    *(f4*)(energy + b * 400 + sc * 8)     = o0;
    *(f4*)(energy + b * 400 + sc * 8 + 4) = o1;
  }
}

// ---------------- K4b: softmax over s (in-place), also writes enc_attn ----
__global__ __launch_bounds__(256) void k4_softmax(
    float* __restrict__ energy, float* __restrict__ out_attn)
{
  __shared__ float sm[4];
  int b = blockIdx.x, tid = threadIdx.x;
  float* e = energy + b * 400;
  float e0 = (tid < 400)       ? e[tid]       : NEGBIG;
  float e1 = (tid + 256 < 400) ? e[tid + 256] : NEGBIG;
  float m = fmaxf(e0, e1);
#pragma unroll
  for (int o = 32; o; o >>= 1) m = fmaxf(m, __shfl_xor(m, o));
  if ((tid & 63) == 0) sm[tid >> 6] = m;
  __syncthreads();
  m = fmaxf(fmaxf(sm[0], sm[1]), fmaxf(sm[2], sm[3]));
  __syncthreads();
  float x0 = (tid < 400)       ? expf(e0 - m) : 0.f;
  float x1 = (tid + 256 < 400) ? expf(e1 - m) : 0.f;
  float s = x0 + x1;
#pragma unroll
  for (int o = 32; o; o >>= 1) s += __shfl_xor(s, o);
  if ((tid & 63) == 0) sm[tid >> 6] = s;
  __syncthreads();
  s = sm[0] + sm[1] + sm[2] + sm[3];
  float inv = 1.f / s;
  if (tid < 400)       { float a = x0 * inv; e[tid] = a;       out_attn[b * 400 + tid] = a; }
  if (tid + 256 < 400) { float a = x1 * inv; e[tid + 256] = a; out_attn[b * 400 + tid + 256] = a; }
}

// ---------------- K4c: partial context over s-quarters --------------------
// grid (8, 128): blockIdx.x = ht (0..1) | sq (0..3); P[(sq*128+b)*2+ht][256]
__global__ __launch_bounds__(256) void k4_context(
    const float* __restrict__ enc, const float* __restrict__ attn,
    float* __restrict__ P)
{
  __shared__ float at[100];
  int b = blockIdx.y, ht = blockIdx.x & 1, sq = blockIdx.x >> 1;
  int tid = threadIdx.x;
  if (tid < 100) at[tid] = attn[b * 400 + sq * 100 + tid];
  __syncthreads();
  int h = ht * 256 + tid;
  const float* ep = enc + (size_t)(sq * 100 * 128 + b) * 512 + h;
  float acc = 0.f;
#pragma unroll 10
  for (int s = 0; s < 100; s++) acc += at[s] * ep[(size_t)s * 65536];
  P[(size_t)((sq * 128 + b) * 2 + ht) * 256 + tid] = acc;
}

// ---------------- K4d: merge partials -> comb/cbf ----------------
__global__ __launch_bounds__(256) void k4_ctxsum(
    const float* __restrict__ P, float* __restrict__ comb,
    unsigned short* __restrict__ cbf)
{
  int i = blockIdx.x * 256 + threadIdx.x;   // 65536
  int b = i >> 9, j = i & 511;
  int ht = j >> 8, tt = j & 255;
  float s = 0.f;
#pragma unroll
  for (int q = 0; q < 4; q++) s += P[(size_t)((q * 128 + b) * 2 + ht) * 256 + tt];
  comb[b * 1024 + 512 + j] = s;
  cbf[fragidx(b, 512 + j)] = f2bf(s);
}

// ---------------- K_p: prob_ptr ----------------
__global__ __launch_bounds__(64) void k_pptr(
    const float* __restrict__ comb, const float* __restrict__ Wptr,
    const float* __restrict__ bptr, float* __restrict__ out_p,
    float* __restrict__ p)
{
  int b = blockIdx.x, lane = threadIdx.x;
  const float* x = comb + b * 1024;
  float d = 0.f;
#pragma unroll
  for (int i = 0; i < 16; i++) d += x[i * 64 + lane] * Wptr[i * 64 + lane];
#pragma unroll
  for (int o = 32; o; o >>= 1) d += __shfl_xor(d, o);
  if (lane == 0) {
    float pv = 1.f / (1.f + expf(-(d + bptr[0])));
    out_p[b] = pv;
    p[b] = pv;
  }
}

// ---------------- K5a: logits GEMM + fused per-block softmax partials -----
// A (frag-order bf16) staged in LDS per BK=128 chunk; wave covers 32 v.
// W: full-chunk register prefetch (16 f4/lane), next chunk posted during
// MFMA t-loop -> ~16KB/wave in flight, BW-bound on the 204.8MB W stream.
// Epilogue: per-(b-row) max/sumexp partial over this wave's 32 v -> pMS.
__global__ __launch_bounds__(128, 2) void k5_logits(
    const unsigned short* __restrict__ Abf, const float* __restrict__ W,
    const float* __restrict__ bout, float* __restrict__ out,
    float* __restrict__ pMS)
{
  __shared__ __align__(16) unsigned short As[16384];  // 32 KB chunk
  const int tid = threadIdx.x;
  const int wid = tid >> 6, lane = tid & 63;
  const int quad = lane >> 4, l16 = lane & 15;
  const int vb = blockIdx.x * 64 + wid * 32;
  const int v0 = vb + l16;
  const int v1 = vb + 16 + l16;
  const bool ok0 = v0 < NV, ok1 = v1 < NV;
  const size_t r0 = (size_t)(ok0 ? v0 : NV - 1) * 1024 + quad * 8;
  const size_t r1 = (size_t)(ok1 ? v1 : NV - 1) * 1024 + quad * 8;
  f4 acc0[8] = {}, acc1[8] = {};
  f4 w0[8], w1[8];
#pragma unroll
  for (int t = 0; t < 4; t++) {
    w0[2*t]   = *(const f4*)(W + r0 + t * 32);
    w0[2*t+1] = *(const f4*)(W + r0 + t * 32 + 4);
    w1[2*t]   = *(const f4*)(W + r1 + t * 32);
    w1[2*t+1] = *(const f4*)(W + r1 + t * 32 + 4);
  }
  for (int c = 0; c < 8; c++) {
    // stage A chunk c (regs -> LDS)
    const f4* src = (const f4*)(Abf + c * 16384);
    f4* dst = (f4*)As;
    f4 st[16];
#pragma unroll
    for (int j = 0; j < 16; j++) st[j] = src[j * 128 + tid];
    __syncthreads();   // previous chunk's readers done
#pragma unroll
    for (int j = 0; j < 16; j++) dst[j * 128 + tid] = st[j];
    // convert current chunk's W to bf16 B-fragments
    short8 B0[4], B1[4];
#pragma unroll
    for (int t = 0; t < 4; t++) {
      f4 a = w0[2*t], b = w0[2*t+1], cfl = w1[2*t], d = w1[2*t+1];
      B0[t][0] = (short)f2bf(a[0]); B0[t][1] = (short)f2bf(a[1]);
      B0[t][2] = (short)f2bf(a[2]); B0[t][3] = (short)f2bf(a[3]);
      B0[t][4] = (short)f2bf(b[0]); B0[t][5] = (short)f2bf(b[1]);
      B0[t][6] = (short)f2bf(b[2]); B0[t][7] = (short)f2bf(b[3]);
      B1[t][0] = (short)f2bf(cfl[0]); B1[t][1] = (short)f2bf(cfl[1]);
      B1[t][2] = (short)f2bf(cfl[2]); B1[t][3] = (short)f2bf(cfl[3]);
      B1[t][4] = (short)f2bf(d[0]); B1[t][5] = (short)f2bf(d[1]);
      B1[t][6] = (short)f2bf(d[2]); B1[t][7] = (short)f2bf(d[3]);
    }
    // prefetch next chunk's W (in flight across the t-loop)
    if (c < 7) {
      const float* p0 = W + r0 + (c + 1) * 128;
      const float* p1 = W + r1 + (c + 1) * 128;
#pragma unroll
      for (int t = 0; t < 4; t++) {
        w0[2*t]   = *(const f4*)(p0 + t * 32);
        w0[2*t+1] = *(const f4*)(p0 + t * 32 + 4);
        w1[2*t]   = *(const f4*)(p1 + t * 32);
        w1[2*t+1] = *(const f4*)(p1 + t * 32 + 4);
      }
    }
    __syncthreads();   // A staged
#pragma unroll
    for (int t = 0; t < 4; t++) {
      const short8* afp = (const short8*)(As + t * 4096);
#pragma unroll
      for (int mt = 0; mt < 8; mt++) {
        short8 af = afp[mt * 64 + lane];
        acc0[mt] = __builtin_amdgcn_mfma_f32_16x16x32_bf16(af, B0[t], acc0[mt], 0, 0, 0);
        acc1[mt] = __builtin_amdgcn_mfma_f32_16x16x32_bf16(af, B1[t], acc1[mt], 0, 0, 0);
      }
    }
  }
  float bias0 = ok0 ? bout[v0] : 0.f;
  float bias1 = ok1 ? bout[v1] : 0.f;
#pragma unroll
  for (int mt = 0; mt < 8; mt++) {
#pragma unroll
    for (int r = 0; r < 4; r++) {
      int brow = mt * 16 + quad * 4 + r;   // C/D: col=lane&15, row=quad*4+reg
      float a0 = ok0 ? acc0[mt][r] + bias0 : NEGBIG;
      float a1 = ok1 ? acc1[mt][r] + bias1 : NEGBIG;
      if (ok0) out[(size_t)brow * NV + v0] = a0;
      if (ok1) out[(size_t)brow * NV + v1] = a1;
      float m = fmaxf(a0, a1);
#pragma unroll
      for (int o = 8; o; o >>= 1) m = fmaxf(m, __shfl_xor(m, o));
      float s = (ok0 ? expf(a0 - m) : 0.f) + (ok1 ? expf(a1 - m) : 0.f);
#pragma unroll
      for (int o = 8; o; o >>= 1) s += __shfl_xor(s, o);
      if (l16 == 0) {
        f2 ms; ms[0] = m; ms[1] = s;
        *(f2*)(pMS + (size_t)brow * 3200 + (blockIdx.x * 2 + wid) * 2) = ms;
      }
    }
  }
}

// ---------------- K5b: reduce partials -> t[b] ----------------
__global__ __launch_bounds__(256) void k5_reduce(
    const float* __restrict__ pMS, const float* __restrict__ p,
    float* __restrict__ t)
{
  __shared__ float sm[4];
  int b = blockIdx.x, tid = threadIdx.x;
  const f2* q = (const f2*)(pMS + (size_t)b * 3200);
  float M = NEGBIG;
  for (int i = tid; i < 1564; i += 256) M = fmaxf(M, q[i][0]);
#pragma unroll
  for (int o = 32; o; o >>= 1) M = fmaxf(M, __shfl_xor(M, o));
  if ((tid & 63) == 0) sm[tid >> 6] = M;
  __syncthreads();
  M = fmaxf(fmaxf(sm[0], sm[1]), fmaxf(sm[2], sm[3]));
  __syncthreads();
  float S = 0.f;
  for (int i = tid; i < 1564; i += 256) {
    f2 v = q[i];
    S += v[1] * expf(v[0] - M);
  }
#pragma unroll
  for (int o = 32; o; o >>= 1) S += __shfl_xor(S, o);
  if ((tid & 63) == 0) sm[tid >> 6] = S;
  __syncthreads();
  if (tid == 0) {
    float Sf = sm[0] + sm[1] + sm[2] + sm[3];
    t[b] = -M - logf(Sf) + logf(1.f - p[b]);
  }
}

// ---------------- K5d: out = logit + t[b]  (== log((1-p)*gen)) ------------
__global__ __launch_bounds__(256) void k5_shift(
    float* __restrict__ out, const float* __restrict__ t)
{
  int vv = blockIdx.x * 256 + threadIdx.x;
  int b = blockIdx.y;
  if (vv < NV) out[(size_t)b * NV + vv] += t[b];
}

// ---------------- K5e: sparse pointer mix via CAS: log(exp(x)+p*attn) -----
__global__ __launch_bounds__(256) void k5_scatter(
    const int* __restrict__ idx, const float* __restrict__ p,
    const float* __restrict__ attn, float* __restrict__ out)
{
  int i = blockIdx.x * 256 + threadIdx.x;
  if (i >= NS * NB) return;
  int s = i >> 7, b = i & 127;            // idx layout (S,B)
  float add = p[b] * attn[b * 400 + s];
  int* ai = (int*)(out + (size_t)b * NV + idx[i]);
  int cur = *ai;
  while (true) {
    float oldf = __int_as_float(cur);
    float nv = logf(expf(oldf) + add);
    int got = atomicCAS(ai, cur, __float_as_int(nv));
    if (got == cur) break;
    cur = got;
  }
}

extern "C" void kernel_launch(void* const* d_in, const int* in_sizes, int n_in,
                              void* d_out, int out_size, void* d_ws, size_t ws_size,
                              hipStream_t stream) {
  (void)in_sizes; (void)n_in; (void)out_size; (void)ws_size;
  const float* emb  = (const float*)d_in[0];
  const float* hid  = (const float*)d_in[1];
  const float* enc  = (const float*)d_in[2];
  const int*   widx = (const int*)d_in[3];
  const float* Wih  = (const float*)d_in[5];
  const float* Whh  = (const float*)d_in[6];
  const float* bih  = (const float*)d_in[7];
  const float* bhh  = (const float*)d_in[8];
  const float* Wbil = (const float*)d_in[9];
  const float* bbil = (const float*)d_in[10];
  const float* Wout = (const float*)d_in[11];
  const float* bout = (const float*)d_in[12];
  const float* Wptr = (const float*)d_in[13];
  const float* bptr = (const float*)d_in[14];

  float* out      = (float*)d_out;
  float* out_logp = out;                 // 128*50000
  float* out_h    = out + 6400000;       // 128*512
  float* out_attn = out + 6465536;       // 128*400
  float* out_p    = out + 6516736;       // 128

  float* ws   = (float*)d_ws;
  float* gigh = ws;                      // 393216
  float* comb = ws + 393216;             // 131072
  float* vws  = ws + 524288;             // 65536
  float* attn = ws + 589824;             // 51200
  float* pws  = ws + 641024;             // 128
  float* tws  = ws + 641152;             // 128
  unsigned short* cbf = (unsigned short*)(ws + 641280);  // 131072 ushorts (65536 f32)
  float* Pctx = ws + 706816;             // 262144 (4*128*512)
  float* pMS  = ws + 968960;             // 409600 (128*3200)

  k1_gigh   <<<dim3(96, 2),    256, 0, stream>>>(emb, hid, Wih, Whh, gigh);
  k2_gates  <<<256,            256, 0, stream>>>(gigh, hid, bih, bhh, out_h, comb, cbf);
  k3_v      <<<256,            256, 0, stream>>>(comb, Wbil, vws);
  k4_energy <<<dim3(25, 128),  128, 0, stream>>>(enc, vws, bbil, attn);
  k4_softmax<<<128,            256, 0, stream>>>(attn, out_attn);
  k4_context<<<dim3(8, 128),   256, 0, stream>>>(enc, attn, Pctx);
  k4_ctxsum <<<256,            256, 0, stream>>>(Pctx, comb, cbf);
  k_pptr    <<<128,             64, 0, stream>>>(comb, Wptr, bptr, out_p, pws);
  k5_logits <<<782,            128, 0, stream>>>(cbf, Wout, bout, out_logp, pMS);
  k5_reduce <<<128,            256, 0, stream>>>(pMS, pws, tws);
  k5_shift  <<<dim3(196, 128), 256, 0, stream>>>(out_logp, tws);
  k5_scatter<<<200,            256, 0, stream>>>(widx, pws, attn, out_logp);
}

// Round 4
// 494.993 us; speedup vs baseline: 1.3888x; 1.0273x over previous
//
#include <hip/hip_runtime.h>
#include <cstdint>
#include <cstddef>

typedef float f4 __attribute__((ext_vector_type(4)));
typedef float f2 __attribute__((ext_vector_type(2)));
typedef short short8 __attribute__((ext_vector_type(8)));

#define NB 128
#define NH 512
#define NS 400
#define NV 50000
#define NEGBIG (-3.402823466e38f)

__device__ __forceinline__ unsigned short f2bf(float f) {
  unsigned u = __float_as_uint(f);
  u = u + 0x7fffu + ((u >> 16) & 1u);   // RTNE
  return (unsigned short)(u >> 16);
}

// async global->LDS, 16B per lane (wave-uniform base + lane*16 layout)
__device__ __forceinline__ void load_lds16(const f4* g, f4* l) {
  __builtin_amdgcn_global_load_lds(
      (const __attribute__((address_space(1))) unsigned int*)g,
      (__attribute__((address_space(3))) unsigned int*)l, 16, 0, 0);
}

// bf16 A staged in MFMA-fragment order so k5 can ds_read_b128 contiguously.
// chunk c = k>>7 (BK=128), step t = (k>>5)&3, quad q = (k>>3)&3, o = k&7,
// mt = m>>4, l16 = m&15.
__device__ __forceinline__ int fragidx(int m, int k) {
  int c = k >> 7;
  int t = (k >> 5) & 3;
  int q = (k >> 3) & 3;
  int o = k & 7;
  return ((((c * 4 + t) * 8 + (m >> 4)) * 64) + q * 16 + (m & 15)) * 8 + o;
}

// ---------------- K1: gi/gh GEMMs ----------------
__global__ __launch_bounds__(256) void k1_gigh(
    const float* __restrict__ emb, const float* __restrict__ hid,
    const float* __restrict__ Wih, const float* __restrict__ Whh,
    float* __restrict__ C)
{
  __shared__ float As[32 * 68];   // [k][m], padded
  __shared__ float Bs[32 * 36];   // [k][n], padded
  const int tid = threadIdx.x;
  const int n0g = blockIdx.x * 32;
  const int m0  = blockIdx.y * 64;
  const float* A; const float* Bm; int n0;
  if (n0g < 1536) { A = emb; Bm = Wih; n0 = n0g; }
  else            { A = hid; Bm = Whh; n0 = n0g - 1536; }
  const int mt = tid & 15, nt = tid >> 4;
  const int arow = tid >> 2, ac = tid & 3;
  const int brow = tid >> 3, bc = tid & 7;
  float acc[4][2] = {};
  for (int k0 = 0; k0 < 512; k0 += 32) {
    f4 x0 = *(const f4*)(A + (m0 + arow) * 512 + k0 + ac * 8);
    f4 x1 = *(const f4*)(A + (m0 + arow) * 512 + k0 + ac * 8 + 4);
    f4 y  = *(const f4*)(Bm + (n0 + brow) * 512 + k0 + bc * 4);
    __syncthreads();
#pragma unroll
    for (int kk = 0; kk < 4; kk++) {
      As[(ac * 8 + kk) * 68 + arow]     = x0[kk];
      As[(ac * 8 + 4 + kk) * 68 + arow] = x1[kk];
      Bs[(bc * 4 + kk) * 36 + brow]     = y[kk];
    }
    __syncthreads();
#pragma unroll
    for (int kk = 0; kk < 32; kk++) {
      f4 a = *(const f4*)(As + kk * 68 + mt * 4);
      f2 b = *(const f2*)(Bs + kk * 36 + nt * 2);
#pragma unroll
      for (int i = 0; i < 4; i++) {
        acc[i][0] += a[i] * b[0];
        acc[i][1] += a[i] * b[1];
      }
    }
  }
#pragma unroll
  for (int i = 0; i < 4; i++) {
    f2 o; o[0] = acc[i][0]; o[1] = acc[i][1];
    *(f2*)(C + (size_t)(m0 + mt * 4 + i) * 3072 + n0g + nt * 2) = o;
  }
}

// ---------------- K2: GRU gates -> h_new ----------------
__global__ __launch_bounds__(256) void k2_gates(
    const float* __restrict__ gigh, const float* __restrict__ hid,
    const float* __restrict__ bih, const float* __restrict__ bhh,
    float* __restrict__ out_h, float* __restrict__ comb,
    unsigned short* __restrict__ cbf)
{
  int i = blockIdx.x * 256 + threadIdx.x;   // 65536
  int b = i >> 9, j = i & 511;
  const float* gg = gigh + b * 3072;
  float ir  = gg[j]        + bih[j];
  float iz  = gg[j + 512]  + bih[j + 512];
  float in_ = gg[j + 1024] + bih[j + 1024];
  float hr  = gg[j + 1536] + bhh[j];
  float hz  = gg[j + 2048] + bhh[j + 512];
  float hn  = gg[j + 2560] + bhh[j + 1024];
  float r = 1.f / (1.f + expf(-(ir + hr)));
  float z = 1.f / (1.f + expf(-(iz + hz)));
  float n = tanhf(in_ + r * hn);
  float hnew = (1.f - z) * n + z * hid[i];
  out_h[i] = hnew;
  comb[b * 1024 + j] = hnew;
  cbf[fragidx(b, j)] = f2bf(hnew);
}

// ---------------- K3: v = h_new @ W_bil (NN, coalesced j) ----------------
__global__ __launch_bounds__(256) void k3_v(
    const float* __restrict__ comb, const float* __restrict__ Wbil,
    float* __restrict__ v)
{
  int i = blockIdx.x * 256 + threadIdx.x;   // 65536
  int b = i >> 9, j = i & 511;
  const float* x = comb + b * 1024;         // h_new part
  float acc = 0.f;
#pragma unroll 16
  for (int h = 0; h < 512; h++) acc += x[h] * Wbil[h * 512 + j];
  v[i] = acc;
}

// ---------------- K4a: energy[s,b] — one wave per (b, 8 s-values) ---------
__global__ __launch_bounds__(128) void k4_energy(
    const float* __restrict__ enc, const float* __restrict__ v,
    const float* __restrict__ bbil, float* __restrict__ energy)  // [b][400]
{
  int tid = threadIdx.x;
  int wid = tid >> 6, lane = tid & 63;
  int b = blockIdx.y;
  int sc = blockIdx.x * 2 + wid;            // 0..49
  const float* vr = v + b * 512 + lane * 8;
  f4 v0 = *(const f4*)vr, v1 = *(const f4*)(vr + 4);
  float e[8];
#pragma unroll
  for (int i = 0; i < 8; i++) {
    int s = sc * 8 + i;
    const float* er = enc + ((size_t)(s * 128 + b)) * 512 + lane * 8;
    f4 e0 = *(const f4*)er, e1 = *(const f4*)(er + 4);
    e[i] = e0[0]*v0[0] + e0[1]*v0[1] + e0[2]*v0[2] + e0[3]*v0[3]
         + e1[0]*v1[0] + e1[1]*v1[1] + e1[2]*v1[2] + e1[3]*v1[3];
  }
#pragma unroll
  for (int i = 0; i < 8; i++)
#pragma unroll
    for (int o = 32; o; o >>= 1) e[i] += __shfl_xor(e[i], o);
  if (lane == 0) {
    float bb = bbil[0];
    f4 o0, o1;
    o0[0] = e[0] + bb; o0[1] = e[1] + bb; o0[2] = e[2] + bb; o0[3] = e[3] + bb;
    o1[0] = e[4] + bb; o1[1] = e[5] + bb; o1[2] = e[6] + bb; o1[3] = e[7] + bb;
    *(f4*)(energy + b * 400 + sc * 8)     = o0;
    *(f4*)(energy + b * 400 + sc * 8 + 4) = o1;
  }
}

// ---------------- K4b: fused softmax + partial context --------------------
// grid (8, 128): blockIdx.x = ht (bit0) | sq<<1. Each block redundantly
// reduces the 400 energies (L2-hot, 1.6KB) -> m,S; sq/ht==0 blocks write
// out_attn quarters; then partial context over its s-quarter.
__global__ __launch_bounds__(256) void k4_ctx(
    const float* __restrict__ enc, const float* __restrict__ energy,
    float* __restrict__ out_attn, float* __restrict__ P)
{
  __shared__ float sm[4];
  __shared__ float at[100];
  int b = blockIdx.y, ht = blockIdx.x & 1, sq = blockIdx.x >> 1;
  int tid = threadIdx.x;
  const float* E = energy + b * 400;
  float e0 = E[tid];
  float e1 = (tid + 256 < 400) ? E[tid + 256] : NEGBIG;
  float m = fmaxf(e0, e1);
#pragma unroll
  for (int o = 32; o; o >>= 1) m = fmaxf(m, __shfl_xor(m, o));
  if ((tid & 63) == 0) sm[tid >> 6] = m;
  __syncthreads();
  m = fmaxf(fmaxf(sm[0], sm[1]), fmaxf(sm[2], sm[3]));
  __syncthreads();
  float x = expf(e0 - m) + ((tid + 256 < 400) ? expf(e1 - m) : 0.f);
#pragma unroll
  for (int o = 32; o; o >>= 1) x += __shfl_xor(x, o);
  if ((tid & 63) == 0) sm[tid >> 6] = x;
  __syncthreads();
  float invS = 1.f / (sm[0] + sm[1] + sm[2] + sm[3]);
  if (tid < 100) {
    float a = expf(E[sq * 100 + tid] - m) * invS;
    at[tid] = a;
    if (ht == 0) out_attn[b * 400 + sq * 100 + tid] = a;
  }
  __syncthreads();
  int h = ht * 256 + tid;
  const float* ep = enc + (size_t)(sq * 100 * 128 + b) * 512 + h;
  float acc = 0.f;
#pragma unroll 10
  for (int s = 0; s < 100; s++) acc += at[s] * ep[(size_t)s * 65536];
  P[(size_t)((sq * 128 + b) * 2 + ht) * 256 + tid] = acc;
}

// ---------------- K4c: merge partials -> comb/cbf + fused prob_ptr --------
// one block per b (128 blocks x 256 thr)
__global__ __launch_bounds__(256) void k4_cp(
    const float* __restrict__ P, const float* __restrict__ comb_in,
    const float* __restrict__ Wptr, const float* __restrict__ bptr,
    float* __restrict__ comb, unsigned short* __restrict__ cbf,
    float* __restrict__ out_p, float* __restrict__ pw)
{
  __shared__ float sm[4];
  int b = blockIdx.x, tid = threadIdx.x;
  float dot = 0.f;
#pragma unroll
  for (int half = 0; half < 2; half++) {
    int j = tid + half * 256;
    int ht = j >> 8, tt = j & 255;
    float s = 0.f;
#pragma unroll
    for (int q = 0; q < 4; q++) s += P[(size_t)((q * 128 + b) * 2 + ht) * 256 + tt];
    comb[b * 1024 + 512 + j] = s;
    cbf[fragidx(b, 512 + j)] = f2bf(s);
    dot += s * Wptr[512 + j];
    dot += comb_in[b * 1024 + j] * Wptr[j];
  }
#pragma unroll
  for (int o = 32; o; o >>= 1) dot += __shfl_xor(dot, o);
  if ((tid & 63) == 0) sm[tid >> 6] = dot;
  __syncthreads();
  if (tid == 0) {
    float d = sm[0] + sm[1] + sm[2] + sm[3];
    float pv = 1.f / (1.f + expf(-(d + bptr[0])));
    out_p[b] = pv;
    pw[b] = pv;
  }
}

// ---------------- K5a: logits GEMM + fused per-block softmax partials -----
// A (frag-order bf16) staged via global_load_lds per BK=128 chunk (32KB);
// wave covers 32 v. W: full-chunk register prefetch issued after the stage
// barrier so it drains during the MFMA t-loop.
__global__ __launch_bounds__(128, 2) void k5_logits(
    const unsigned short* __restrict__ Abf, const float* __restrict__ W,
    const float* __restrict__ bout, float* __restrict__ out,
    float* __restrict__ pMS)
{
  __shared__ __align__(16) unsigned short As[16384];  // 32 KB chunk
  const int tid = threadIdx.x;
  const int wid = tid >> 6, lane = tid & 63;
  const int quad = lane >> 4, l16 = lane & 15;
  const int vb = blockIdx.x * 64 + wid * 32;
  const int v0 = vb + l16;
  const int v1 = vb + 16 + l16;
  const bool ok0 = v0 < NV, ok1 = v1 < NV;
  const size_t r0 = (size_t)(ok0 ? v0 : NV - 1) * 1024 + quad * 8;
  const size_t r1 = (size_t)(ok1 ? v1 : NV - 1) * 1024 + quad * 8;
  f4 acc0[8] = {}, acc1[8] = {};
  f4 w0[8], w1[8];
#pragma unroll
  for (int t = 0; t < 4; t++) {
    w0[2*t]   = *(const f4*)(W + r0 + t * 32);
    w0[2*t+1] = *(const f4*)(W + r0 + t * 32 + 4);
    w1[2*t]   = *(const f4*)(W + r1 + t * 32);
    w1[2*t+1] = *(const f4*)(W + r1 + t * 32 + 4);
  }
  for (int c = 0; c < 8; c++) {
    const f4* src = (const f4*)(Abf + c * 16384);
    f4* dst = (f4*)As;
    __syncthreads();   // previous chunk's readers done
#pragma unroll
    for (int j = 0; j < 16; j++) load_lds16(src + j * 128 + tid, dst + j * 128 + tid);
    // convert current chunk's W to bf16 B-fragments
    short8 B0[4], B1[4];
#pragma unroll
    for (int t = 0; t < 4; t++) {
      f4 a = w0[2*t], b = w0[2*t+1], cfl = w1[2*t], d = w1[2*t+1];
      B0[t][0] = (short)f2bf(a[0]); B0[t][1] = (short)f2bf(a[1]);
      B0[t][2] = (short)f2bf(a[2]); B0[t][3] = (short)f2bf(a[3]);
      B0[t][4] = (short)f2bf(b[0]); B0[t][5] = (short)f2bf(b[1]);
      B0[t][6] = (short)f2bf(b[2]); B0[t][7] = (short)f2bf(b[3]);
      B1[t][0] = (short)f2bf(cfl[0]); B1[t][1] = (short)f2bf(cfl[1]);
      B1[t][2] = (short)f2bf(cfl[2]); B1[t][3] = (short)f2bf(cfl[3]);
      B1[t][4] = (short)f2bf(d[0]); B1[t][5] = (short)f2bf(d[1]);
      B1[t][6] = (short)f2bf(d[2]); B1[t][7] = (short)f2bf(d[3]);
    }
    __syncthreads();   // A staged (drains global_load_lds)
    // prefetch next chunk's W: in flight across the whole t-loop
    if (c < 7) {
      const float* p0 = W + r0 + (c + 1) * 128;
      const float* p1 = W + r1 + (c + 1) * 128;
#pragma unroll
      for (int t = 0; t < 4; t++) {
        w0[2*t]   = *(const f4*)(p0 + t * 32);
        w0[2*t+1] = *(const f4*)(p0 + t * 32 + 4);
        w1[2*t]   = *(const f4*)(p1 + t * 32);
        w1[2*t+1] = *(const f4*)(p1 + t * 32 + 4);
      }
    }
#pragma unroll
    for (int t = 0; t < 4; t++) {
      const short8* afp = (const short8*)(As + t * 4096);
#pragma unroll
      for (int mt = 0; mt < 8; mt++) {
        short8 af = afp[mt * 64 + lane];
        acc0[mt] = __builtin_amdgcn_mfma_f32_16x16x32_bf16(af, B0[t], acc0[mt], 0, 0, 0);
        acc1[mt] = __builtin_amdgcn_mfma_f32_16x16x32_bf16(af, B1[t], acc1[mt], 0, 0, 0);
      }
    }
  }
  float bias0 = ok0 ? bout[v0] : 0.f;
  float bias1 = ok1 ? bout[v1] : 0.f;
#pragma unroll
  for (int mt = 0; mt < 8; mt++) {
#pragma unroll
    for (int r = 0; r < 4; r++) {
      int brow = mt * 16 + quad * 4 + r;   // C/D: col=lane&15, row=quad*4+reg
      float a0 = ok0 ? acc0[mt][r] + bias0 : NEGBIG;
      float a1 = ok1 ? acc1[mt][r] + bias1 : NEGBIG;
      if (ok0) out[(size_t)brow * NV + v0] = a0;
      if (ok1) out[(size_t)brow * NV + v1] = a1;
      float m = fmaxf(a0, a1);
#pragma unroll
      for (int o = 8; o; o >>= 1) m = fmaxf(m, __shfl_xor(m, o));
      float s = (ok0 ? expf(a0 - m) : 0.f) + (ok1 ? expf(a1 - m) : 0.f);
#pragma unroll
      for (int o = 8; o; o >>= 1) s += __shfl_xor(s, o);
      if (l16 == 0) {
        f2 ms; ms[0] = m; ms[1] = s;
        *(f2*)(pMS + (size_t)brow * 3200 + (blockIdx.x * 2 + wid) * 2) = ms;
      }
    }
  }
}

// ---------------- K5b: fused reduce + shift ----------------
// grid (8, 128): each block redundantly reduces pMS row b (12.5KB, L2-hot),
// then shifts its 6250-element segment of out.
__global__ __launch_bounds__(256) void k5_shift(
    float* __restrict__ out, const float* __restrict__ pMS,
    const float* __restrict__ p)
{
  __shared__ float sm[4];
  int b = blockIdx.y, seg = blockIdx.x, tid = threadIdx.x;
  const f2* q = (const f2*)(pMS + (size_t)b * 3200);
  float M = NEGBIG;
  for (int i = tid; i < 1564; i += 256) M = fmaxf(M, q[i][0]);
#pragma unroll
  for (int o = 32; o; o >>= 1) M = fmaxf(M, __shfl_xor(M, o));
  if ((tid & 63) == 0) sm[tid >> 6] = M;
  __syncthreads();
  M = fmaxf(fmaxf(sm[0], sm[1]), fmaxf(sm[2], sm[3]));
  __syncthreads();
  float S = 0.f;
  for (int i = tid; i < 1564; i += 256) {
    f2 v = q[i];
    S += v[1] * expf(v[0] - M);
  }
#pragma unroll
  for (int o = 32; o; o >>= 1) S += __shfl_xor(S, o);
  if ((tid & 63) == 0) sm[tid >> 6] = S;
  __syncthreads();
  float t = -M - logf(sm[0] + sm[1] + sm[2] + sm[3]) + logf(1.f - p[b]);
  float* o = out + (size_t)b * NV + seg * 6250;
  for (int i = tid; i < 6250; i += 256) o[i] += t;
}

// ---------------- K5e: sparse pointer mix via CAS: log(exp(x)+p*attn) -----
__global__ __launch_bounds__(256) void k5_scatter(
    const int* __restrict__ idx, const float* __restrict__ p,
    const float* __restrict__ attn, float* __restrict__ out)
{
  int i = blockIdx.x * 256 + threadIdx.x;
  if (i >= NS * NB) return;
  int s = i >> 7, b = i & 127;            // idx layout (S,B)
  float add = p[b] * attn[b * 400 + s];
  int* ai = (int*)(out + (size_t)b * NV + idx[i]);
  int cur = *ai;
  while (true) {
    float oldf = __int_as_float(cur);
    float nv = logf(expf(oldf) + add);
    int got = atomicCAS(ai, cur, __float_as_int(nv));
    if (got == cur) break;
    cur = got;
  }
}

extern "C" void kernel_launch(void* const* d_in, const int* in_sizes, int n_in,
                              void* d_out, int out_size, void* d_ws, size_t ws_size,
                              hipStream_t stream) {
  (void)in_sizes; (void)n_in; (void)out_size; (void)ws_size;
  const float* emb  = (const float*)d_in[0];
  const float* hid  = (const float*)d_in[1];
  const float* enc  = (const float*)d_in[2];
  const int*   widx = (const int*)d_in[3];
  const float* Wih  = (const float*)d_in[5];
  const float* Whh  = (const float*)d_in[6];
  const float* bih  = (const float*)d_in[7];
  const float* bhh  = (const float*)d_in[8];
  const float* Wbil = (const float*)d_in[9];
  const float* bbil = (const float*)d_in[10];
  const float* Wout = (const float*)d_in[11];
  const float* bout = (const float*)d_in[12];
  const float* Wptr = (const float*)d_in[13];
  const float* bptr = (const float*)d_in[14];

  float* out      = (float*)d_out;
  float* out_logp = out;                 // 128*50000
  float* out_h    = out + 6400000;       // 128*512
  float* out_attn = out + 6465536;       // 128*400
  float* out_p    = out + 6516736;       // 128

  float* ws     = (float*)d_ws;
  float* gigh   = ws;                    // 393216
  float* comb   = ws + 393216;           // 131072
  float* vws    = ws + 524288;           // 65536
  float* energy = ws + 589824;           // 51200
  float* pws    = ws + 641024;           // 128
  unsigned short* cbf = (unsigned short*)(ws + 641280);  // 131072 ushorts
  float* Pctx   = ws + 706816;           // 262144 (4*128*512)
  float* pMS    = ws + 968960;           // 409600 (128*3200)

  k1_gigh   <<<dim3(96, 2),   256, 0, stream>>>(emb, hid, Wih, Whh, gigh);
  k2_gates  <<<256,           256, 0, stream>>>(gigh, hid, bih, bhh, out_h, comb, cbf);
  k3_v      <<<256,           256, 0, stream>>>(comb, Wbil, vws);
  k4_energy <<<dim3(25, 128), 128, 0, stream>>>(enc, vws, bbil, energy);
  k4_ctx    <<<dim3(8, 128),  256, 0, stream>>>(enc, energy, out_attn, Pctx);
  k4_cp     <<<128,           256, 0, stream>>>(Pctx, comb, Wptr, bptr, comb, cbf, out_p, pws);
  k5_logits <<<782,           128, 0, stream>>>(cbf, Wout, bout, out_logp, pMS);
  k5_shift  <<<dim3(8, 128),  256, 0, stream>>>(out_logp, pMS, pws);
  k5_scatter<<<200,           256, 0, stream>>>(widx, pws, out_attn, out_logp);
}